// Round 15
// baseline (114.597 us; speedup 1.0000x reference)
//
#include <hip/hip_runtime.h>
#include <hip/hip_fp16.h>
#include <math.h>

// SpatialSelectiveMRF: s=60000 rows, K=200 comps, dz=64, 3 spatial, n=6 neighbors.
// R15: kd rewritten as bf8 MFMA — one wave per 16-row tile; per neighbor slot j,
// D = Own(16x256 e5m2) x NbrJ(256x16 e5m2), take the diagonal. Zero decode ops;
// A/B use identical (lane,byte)->k addressing so HW byte-order cancels in the dot.
// kp unchanged from R14 (writes e5m2 x1024 rows, pads 208..255 zeroed).
#define KK 200
#define NT 13
#define NNB 6
#define Q8STRIDE 256

typedef __attribute__((ext_vector_type(8))) short short8;
typedef __attribute__((ext_vector_type(4))) float f32x4;
typedef _Float16 half2v __attribute__((ext_vector_type(2)));
typedef __fp16 fp16x2 __attribute__((ext_vector_type(2)));
#define MFMA16 __builtin_amdgcn_mfma_f32_16x16x32_bf16
#define MFMA8  __builtin_amdgcn_mfma_f32_16x16x32_bf8_bf8

union U8 { short8 s; uint4 u; };
union P2U { fp16x2 h; unsigned u; };

__device__ __forceinline__ unsigned short bfh(float f) {
    unsigned u = __float_as_uint(f);
    return (unsigned short)((u + 0x7fffu + ((u >> 16) & 1u)) >> 16);  // RNE
}
__device__ __forceinline__ float bf2f(unsigned short h) {
    return __uint_as_float(((unsigned)h) << 16);
}
__device__ __forceinline__ short8 z8() {
    short8 v;
#pragma unroll
    for (int j = 0; j < 8; ++j) v[j] = 0;
    return v;
}
// trunc hi/lo split of a float PAIR -> packed bf16 words, IN ORDER.
__device__ __forceinline__ void cvp(float f0, float f1, unsigned& hw, unsigned& lw) {
    unsigned u0 = __float_as_uint(f0), u1 = __float_as_uint(f1);
    float l0 = f0 - __uint_as_float(u0 & 0xffff0000u);
    float l1 = f1 - __uint_as_float(u1 & 0xffff0000u);
    hw = __builtin_amdgcn_perm(u1, u0, 0x07060302u);  // {f0.hi16 | f1.hi16<<16}
    lw = __builtin_amdgcn_perm(__float_as_uint(l1), __float_as_uint(l0), 0x07060302u);
}
__device__ __forceinline__ unsigned pkrtz_u(float a, float b) {
    P2U x; x.h = __builtin_amdgcn_cvt_pkrtz(a, b); return x.u;
}

// MFMA 16x16x32 layouts: A: lane holds A[m=lane&15][k=(lane>>4)*8+j];
// B: lane holds B[k=(lane>>4)*8+j][n=lane&15]; D: [row=(lane>>4)*4+r][col=lane&15].
__global__ __launch_bounds__(512, 4) void
k_point(const float* __restrict__ Z, const float* __restrict__ S,
        const float* __restrict__ selmu, const float* __restrict__ spamu,
        unsigned char* __restrict__ Qc8, float* __restrict__ pointbuf,
        int sRows, int mTiles)
{
    __shared__ short8 ldsBh[26 * 64];
    __shared__ short8 ldsBl[26 * 64];
    __shared__ uint2  ldsB2h[NT * 16];
    __shared__ uint2  ldsB2l[NT * 16];
    __shared__ float  normAcc[NT * 16];

    const int tid = threadIdx.x;

    if (tid < NT * 16) normAcc[tid] = 0.f;
    __syncthreads();

    for (int slot = tid; slot < 26 * 64; slot += 512) {
        int L = slot & 63, ts = slot >> 6;
        int t = ts >> 1, sstep = ts & 1;
        int n = t * 16 + (L & 15);
        int kb = sstep * 32 + (L >> 4) * 8;
        U8 hi, lo;
        hi.s = z8(); lo.s = z8();
        if (n < KK) {
            const float* mp = selmu + (size_t)n * 64 + kb;
            float4 a = *(const float4*)mp;
            float4 b = *(const float4*)(mp + 4);
            cvp(a.x, a.y, hi.u.x, lo.u.x);
            cvp(a.z, a.w, hi.u.y, lo.u.y);
            cvp(b.x, b.y, hi.u.z, lo.u.z);
            cvp(b.z, b.w, hi.u.w, lo.u.w);
            float ss = a.x*a.x + a.y*a.y + a.z*a.z + a.w*a.w
                     + b.x*b.x + b.y*b.y + b.z*b.z + b.w*b.w;
            atomicAdd(&normAcc[n], ss);
        }
        ldsBh[slot] = hi.s;
        ldsBl[slot] = lo.s;
    }
    __syncthreads();
    if (tid < NT * 16) {
        int n = tid;
        uint2 vh = make_uint2(0, 0), vl = make_uint2(0, 0);
        if (n < KK) {
            float p0 = spamu[n * 3 + 0], p1 = spamu[n * 3 + 1], p2 = spamu[n * 3 + 2];
            float nrm = -0.5f * (normAcc[n] + p0 * p0 + p1 * p1 + p2 * p2);
            unsigned short h0 = bfh(p0), h1 = bfh(p1), h2 = bfh(p2), h3 = bfh(nrm);
            unsigned short g0 = bfh(p0 - bf2f(h0)), g1 = bfh(p1 - bf2f(h1));
            unsigned short g2 = bfh(p2 - bf2f(h2)), g3 = bfh(nrm - bf2f(h3));
            vh = make_uint2((unsigned)h0 | ((unsigned)h1 << 16), (unsigned)h2 | ((unsigned)h3 << 16));
            vl = make_uint2((unsigned)g0 | ((unsigned)g1 << 16), (unsigned)g2 | ((unsigned)g3 << 16));
        }
        ldsB2h[tid] = vh;
        ldsB2l[tid] = vl;
    }
    __syncthreads();

    const int wave = tid >> 6;
    const int lane = tid & 63;
    const int q = lane >> 4;
    const int li = lane & 15;
    const float cLog = 0.5f * 67.0f * 1.8378770664093453f;

    const int tile = blockIdx.x * 8 + wave;
    if (tile >= mTiles) return;
    const int m0 = tile * 16;
    const int row = m0 + li;
    const int rowA = (row < sRows) ? row : (sRows - 1);

    const float* zr = Z + (size_t)rowA * 64 + q * 8;
    float4 z0 = *(const float4*)zr;
    float4 z1 = *(const float4*)(zr + 4);
    float4 z2 = *(const float4*)(zr + 32);
    float4 z3 = *(const float4*)(zr + 36);
    U8 ah0, al0, ah1, al1;
    cvp(z0.x, z0.y, ah0.u.x, al0.u.x);
    cvp(z0.z, z0.w, ah0.u.y, al0.u.y);
    cvp(z1.x, z1.y, ah0.u.z, al0.u.z);
    cvp(z1.z, z1.w, ah0.u.w, al0.u.w);
    cvp(z2.x, z2.y, ah1.u.x, al1.u.x);
    cvp(z2.z, z2.w, ah1.u.y, al1.u.y);
    cvp(z3.x, z3.y, ah1.u.z, al1.u.z);
    cvp(z3.z, z3.w, ah1.u.w, al1.u.w);

    float zz = z0.x*z0.x + z0.y*z0.y + z0.z*z0.z + z0.w*z0.w
             + z1.x*z1.x + z1.y*z1.y + z1.z*z1.z + z1.w*z1.w
             + z2.x*z2.x + z2.y*z2.y + z2.z*z2.z + z2.w*z2.w
             + z3.x*z3.x + z3.y*z3.y + z3.z*z3.z + z3.w*z3.w;
    zz += __shfl_xor(zz, 16);
    zz += __shfl_xor(zz, 32);

    float s0v = S[(size_t)rowA * 3 + 0];
    float s1v = S[(size_t)rowA * 3 + 1];
    float s2v = S[(size_t)rowA * 3 + 2];
    float cz = 0.5f * (zz + s0v * s0v + s1v * s1v + s2v * s2v) + cLog;

    U8 rsh, rsl;
    rsh.s = z8(); rsl.s = z8();
    if (lane < 16) {
        cvp(s0v, s1v, rsh.u.x, rsl.u.x);
        unsigned hw, lw;
        cvp(s2v, 1.0f, hw, lw);
        rsh.u.y = hw;
        rsl.u.y = lw & 0x0000ffffu;
    }

    f32x4 acc[NT];
#pragma unroll
    for (int t = 0; t < NT; ++t) { f32x4 zv = {0.f, 0.f, 0.f, 0.f}; acc[t] = zv; }

#pragma unroll
    for (int t = 0; t < NT; ++t) {
        short8 b0 = ldsBh[(t * 2 + 0) * 64 + lane];
        short8 b1 = ldsBh[(t * 2 + 1) * 64 + lane];
        short8 c0 = ldsBl[(t * 2 + 0) * 64 + lane];
        short8 c1 = ldsBl[(t * 2 + 1) * 64 + lane];
        uint2 bh2 = make_uint2(0, 0), bl2 = make_uint2(0, 0);
        if (lane < 16) { bh2 = ldsB2h[t * 16 + lane]; bl2 = ldsB2l[t * 16 + lane]; }
        U8 cmh, cml;
        cmh.s = z8(); cml.s = z8();
        cmh.u.x = bh2.x; cmh.u.y = bh2.y;
        cml.u.x = bl2.x; cml.u.y = bl2.y;

        acc[t] = MFMA16(b0, ah0.s, acc[t], 0, 0, 0);
        acc[t] = MFMA16(b1, ah1.s, acc[t], 0, 0, 0);
        acc[t] = MFMA16(b0, al0.s, acc[t], 0, 0, 0);
        acc[t] = MFMA16(b1, al1.s, acc[t], 0, 0, 0);
        acc[t] = MFMA16(c0, ah0.s, acc[t], 0, 0, 0);
        acc[t] = MFMA16(c1, ah1.s, acc[t], 0, 0, 0);
        acc[t] = MFMA16(cmh.s, rsh.s, acc[t], 0, 0, 0);
        acc[t] = MFMA16(cmh.s, rsl.s, acc[t], 0, 0, 0);
        acc[t] = MFMA16(cml.s, rsh.s, acc[t], 0, 0, 0);
    }

    const bool padQ = (q >= 2);
    float mx = -1e30f;
#pragma unroll
    for (int t = 0; t < NT; ++t) {
#pragma unroll
        for (int r = 0; r < 4; ++r) {
            float v = acc[t][r];
            if (t == 12 && padQ) v = -1e30f;
            acc[t][r] = v;
            mx = fmaxf(mx, v);
        }
    }
    mx = fmaxf(mx, __shfl_xor(mx, 16));
    mx = fmaxf(mx, __shfl_xor(mx, 32));
    float sl = 0.f, pl = 0.f;
#pragma unroll
    for (int t = 0; t < NT; ++t) {
#pragma unroll
        for (int r = 0; r < 4; ++r) {
            float v = acc[t][r];
            float ee = __expf(v - mx);
            sl += ee;
            pl = fmaf(ee, v, pl);
            acc[t][r] = ee;
        }
    }
    sl += __shfl_xor(sl, 16);
    sl += __shfl_xor(sl, 32);
    pl += __shfl_xor(pl, 16);
    pl += __shfl_xor(pl, 32);
    float inv = 1.0f / sl;

    if (row < sRows) {
        unsigned char* qp = Qc8 + (size_t)row * Q8STRIDE + q * 4;
#pragma unroll
        for (int t = 0; t < NT; ++t) {
            unsigned w = 0;
            if (t < 12 || !padQ) {
                float c0 = fminf(fmaxf(acc[t][0] * inv, 1e-6f), 1.0f - 1e-6f) * 1024.0f;
                float c1 = fminf(fmaxf(acc[t][1] * inv, 1e-6f), 1.0f - 1e-6f) * 1024.0f;
                float c2 = fminf(fmaxf(acc[t][2] * inv, 1e-6f), 1.0f - 1e-6f) * 1024.0f;
                float c3 = fminf(fmaxf(acc[t][3] * inv, 1e-6f), 1.0f - 1e-6f) * 1024.0f;
                unsigned ua = pkrtz_u(c0, c1);
                unsigned ub = pkrtz_u(c2, c3);
                unsigned t0 = ua + 0x007f007fu + ((ua >> 8) & 0x00010001u);
                unsigned t1 = ub + 0x007f007fu + ((ub >> 8) & 0x00010001u);
                w = __builtin_amdgcn_perm(t1, t0, 0x07050301u);
            }
            *(unsigned*)(qp + t * 16) = w;
        }
        // zero-fill pad comps 208..255 (kd reads full 256B rows into MFMA)
        *(unsigned*)(qp + 13 * 16) = 0u;
        *(unsigned*)(qp + 14 * 16) = 0u;
        *(unsigned*)(qp + 15 * 16) = 0u;
        if (lane < 16) pointbuf[row] = cz - pl * inv;
    }
}

// k_doublet R15: one wave per 16-row tile. For neighbor slot j:
//   A-frag: lane (q,li) holds own-row li bytes [32s + q*8, +8)   (8 e5m2 = i64)
//   B-frag: lane (q,li) holds nbr-row dd(li,j) bytes [32s + q*8, +8)
//   acc_j = sum_s MFMA8(a[s], b[s]) ; diag D[m][m] = own_m . nb_j(m).
// Identical addressing on A and B makes the HW byte->k map cancel.
__global__ __launch_bounds__(512, 4) void
k_doublet(const unsigned char* __restrict__ Qc8, const float* __restrict__ pointbuf,
          const int* __restrict__ D, float* __restrict__ out, int sRows, int mTiles)
{
    const int lane = threadIdx.x & 63;
    const int wave = threadIdx.x >> 6;
    const int q = lane >> 4;
    const int li = lane & 15;
    const int tile = blockIdx.x * 8 + wave;
    if (tile >= mTiles) return;
    const int m0 = tile * 16;
    const int rowL = m0 + li;
    const int rowC = (rowL < sRows) ? rowL : (sRows - 1);
    const float LN2_20 = 13.862943611198906f;   // both operands x1024 -> co x 2^20

    // neighbor ids for row rowL (4-way broadcast across q-lanes; L1-served)
    const int* dp = D + (size_t)rowC * NNB;
    int2 d01 = *(const int2*)dp;
    int2 d23 = *(const int2*)(dp + 2);
    int2 d45 = *(const int2*)(dp + 4);
    const int dj[6] = { d01.x, d01.y, d23.x, d23.y, d45.x, d45.y };

    // own A-frags: 8 x i64 (row rowL, bytes 32s + q*8)
    const unsigned char* orow = Qc8 + (size_t)rowC * Q8STRIDE + q * 8;
    long long a[8];
#pragma unroll
    for (int s = 0; s < 8; ++s) a[s] = *(const long long*)(orow + s * 32);

    f32x4 acc[NNB];
#pragma unroll
    for (int j = 0; j < NNB; ++j) { f32x4 zv = {0.f, 0.f, 0.f, 0.f}; acc[j] = zv; }

    long long b[8], bn[8];
    {
        int dd = (dj[0] >= 0) ? dj[0] : rowC;
        const unsigned char* nrow = Qc8 + (size_t)dd * Q8STRIDE + q * 8;
#pragma unroll
        for (int s = 0; s < 8; ++s) b[s] = *(const long long*)(nrow + s * 32);
    }
#pragma unroll
    for (int j = 0; j < NNB; ++j) {
        if (j < NNB - 1) {
            int dd = (dj[j + 1] >= 0) ? dj[j + 1] : rowC;
            const unsigned char* nrow = Qc8 + (size_t)dd * Q8STRIDE + q * 8;
#pragma unroll
            for (int s = 0; s < 8; ++s) bn[s] = *(const long long*)(nrow + s * 32);
        }
#pragma unroll
        for (int s = 0; s < 8; ++s)
            acc[j] = MFMA8((long)a[s], (long)b[s], acc[j], 0, 0, 0);
#pragma unroll
        for (int s = 0; s < 8; ++s) b[s] = bn[s];
    }

    // diagonal lanes: D[row=q*4+r][col=li] -> diag at li>>2 == q, r = li&3
    if ((li >> 2) == q) {
        const int r = li & 3;
        float dbl = 0.f;
#pragma unroll
        for (int j = 0; j < NNB; ++j) {
            float p = (r == 0) ? acc[j][0] : (r == 1) ? acc[j][1]
                    : (r == 2) ? acc[j][2] : acc[j][3];
            if (dj[j] >= 0) dbl += LN2_20 - __logf(p);
        }
        if (rowL < sRows) out[rowL] = pointbuf[rowL] + dbl;
    }
}

extern "C" void kernel_launch(void* const* d_in, const int* in_sizes, int n_in,
                              void* d_out, int out_size, void* d_ws, size_t ws_size,
                              hipStream_t stream) {
    const float* Z     = (const float*)d_in[0];
    const float* S     = (const float*)d_in[1];
    const int*   D     = (const int*)d_in[2];
    const float* selmu = (const float*)d_in[3];
    const float* spamu = (const float*)d_in[4];
    float* out = (float*)d_out;
    const int s = out_size;                    // 60000

    unsigned char* Qc8 = (unsigned char*)d_ws;                   // s*256 B = 15.36 MB
    float* pointbuf = (float*)((char*)d_ws + (size_t)s * Q8STRIDE);

    const int mTiles = (s + 15) / 16;          // 3750
    const int grid1 = (mTiles + 7) / 8;        // 469
    k_point<<<grid1, 512, 0, stream>>>(Z, S, selmu, spamu, Qc8, pointbuf, s, mTiles);

    k_doublet<<<grid1, 512, 0, stream>>>(Qc8, pointbuf, D, out, s, mTiles);
}

// Round 16
// 101.725 us; speedup vs baseline: 1.1265x; 1.1265x over previous
//
#include <hip/hip_runtime.h>
#include <hip/hip_fp16.h>
#include <math.h>

// SpatialSelectiveMRF: s=60000 rows, K=200 comps, dz=64, 3 spatial, n=6 neighbors.
// R16 == R14 (best known, 101.6 us): R15's MFMA-diag kd regressed (+13 us, worse
// VMEM structure); reverted. kd: 16 lanes/row, 4 rows/wave, uint4 row loads,
// perm e5m2->f16 decode, fdot2 dots, DPP row_ror reduction.
#define KK 200
#define NT 13
#define NNB 6
#define Q8STRIDE 256

typedef __attribute__((ext_vector_type(8))) short short8;
typedef __attribute__((ext_vector_type(4))) float f32x4;
typedef _Float16 half2v __attribute__((ext_vector_type(2)));
typedef __fp16 fp16x2 __attribute__((ext_vector_type(2)));
#define MFMA16 __builtin_amdgcn_mfma_f32_16x16x32_bf16

union U8 { short8 s; uint4 u; };
union H2U { half2v h; unsigned u; };
union P2U { fp16x2 h; unsigned u; };

__device__ __forceinline__ unsigned short bfh(float f) {
    unsigned u = __float_as_uint(f);
    return (unsigned short)((u + 0x7fffu + ((u >> 16) & 1u)) >> 16);  // RNE
}
__device__ __forceinline__ float bf2f(unsigned short h) {
    return __uint_as_float(((unsigned)h) << 16);
}
__device__ __forceinline__ short8 z8() {
    short8 v;
#pragma unroll
    for (int j = 0; j < 8; ++j) v[j] = 0;
    return v;
}
// trunc hi/lo split of a float PAIR -> packed bf16 words, IN ORDER.
__device__ __forceinline__ void cvp(float f0, float f1, unsigned& hw, unsigned& lw) {
    unsigned u0 = __float_as_uint(f0), u1 = __float_as_uint(f1);
    float l0 = f0 - __uint_as_float(u0 & 0xffff0000u);
    float l1 = f1 - __uint_as_float(u1 & 0xffff0000u);
    hw = __builtin_amdgcn_perm(u1, u0, 0x07060302u);  // {f0.hi16 | f1.hi16<<16}
    lw = __builtin_amdgcn_perm(__float_as_uint(l1), __float_as_uint(l0), 0x07060302u);
}
__device__ __forceinline__ unsigned e5pair_lo(unsigned w) {
    return __builtin_amdgcn_perm(w, 0u, 0x05000400u);   // bytes 0,1 -> f16 pair
}
__device__ __forceinline__ unsigned e5pair_hi(unsigned w) {
    return __builtin_amdgcn_perm(w, 0u, 0x07000600u);   // bytes 2,3 -> f16 pair
}
__device__ __forceinline__ half2v as_h2(unsigned u) { H2U x; x.u = u; return x.h; }
__device__ __forceinline__ unsigned pkrtz_u(float a, float b) {
    P2U x; x.h = __builtin_amdgcn_cvt_pkrtz(a, b); return x.u;
}
// add value rotated within the 16-lane DPP row (row_ror:n -> ctrl 0x120+n)
#define DPP_ROR_ADD(t, ctrl)                                                        \
    t += __int_as_float(__builtin_amdgcn_update_dpp(0, __float_as_int(t), (ctrl),   \
                                                    0xF, 0xF, true))

// MFMA 16x16x32 layouts: A: lane holds A[m=lane&15][k=(lane>>4)*8+j];
// B: lane holds B[k=(lane>>4)*8+j][n=lane&15]; D: [row=(lane>>4)*4+r][col=lane&15].
__global__ __launch_bounds__(512, 4) void
k_point(const float* __restrict__ Z, const float* __restrict__ S,
        const float* __restrict__ selmu, const float* __restrict__ spamu,
        unsigned char* __restrict__ Qc8, float* __restrict__ pointbuf,
        int sRows, int mTiles)
{
    __shared__ short8 ldsBh[26 * 64];
    __shared__ short8 ldsBl[26 * 64];
    __shared__ uint2  ldsB2h[NT * 16];
    __shared__ uint2  ldsB2l[NT * 16];
    __shared__ float  normAcc[NT * 16];

    const int tid = threadIdx.x;

    if (tid < NT * 16) normAcc[tid] = 0.f;
    __syncthreads();

    for (int slot = tid; slot < 26 * 64; slot += 512) {
        int L = slot & 63, ts = slot >> 6;
        int t = ts >> 1, sstep = ts & 1;
        int n = t * 16 + (L & 15);
        int kb = sstep * 32 + (L >> 4) * 8;
        U8 hi, lo;
        hi.s = z8(); lo.s = z8();
        if (n < KK) {
            const float* mp = selmu + (size_t)n * 64 + kb;
            float4 a = *(const float4*)mp;
            float4 b = *(const float4*)(mp + 4);
            cvp(a.x, a.y, hi.u.x, lo.u.x);
            cvp(a.z, a.w, hi.u.y, lo.u.y);
            cvp(b.x, b.y, hi.u.z, lo.u.z);
            cvp(b.z, b.w, hi.u.w, lo.u.w);
            float ss = a.x*a.x + a.y*a.y + a.z*a.z + a.w*a.w
                     + b.x*b.x + b.y*b.y + b.z*b.z + b.w*b.w;
            atomicAdd(&normAcc[n], ss);
        }
        ldsBh[slot] = hi.s;
        ldsBl[slot] = lo.s;
    }
    __syncthreads();
    if (tid < NT * 16) {
        int n = tid;
        uint2 vh = make_uint2(0, 0), vl = make_uint2(0, 0);
        if (n < KK) {
            float p0 = spamu[n * 3 + 0], p1 = spamu[n * 3 + 1], p2 = spamu[n * 3 + 2];
            float nrm = -0.5f * (normAcc[n] + p0 * p0 + p1 * p1 + p2 * p2);
            unsigned short h0 = bfh(p0), h1 = bfh(p1), h2 = bfh(p2), h3 = bfh(nrm);
            unsigned short g0 = bfh(p0 - bf2f(h0)), g1 = bfh(p1 - bf2f(h1));
            unsigned short g2 = bfh(p2 - bf2f(h2)), g3 = bfh(nrm - bf2f(h3));
            vh = make_uint2((unsigned)h0 | ((unsigned)h1 << 16), (unsigned)h2 | ((unsigned)h3 << 16));
            vl = make_uint2((unsigned)g0 | ((unsigned)g1 << 16), (unsigned)g2 | ((unsigned)g3 << 16));
        }
        ldsB2h[tid] = vh;
        ldsB2l[tid] = vl;
    }
    __syncthreads();

    const int wave = tid >> 6;
    const int lane = tid & 63;
    const int q = lane >> 4;
    const int li = lane & 15;
    const float cLog = 0.5f * 67.0f * 1.8378770664093453f;

    const int tile = blockIdx.x * 8 + wave;
    if (tile >= mTiles) return;
    const int m0 = tile * 16;
    const int row = m0 + li;
    const int rowA = (row < sRows) ? row : (sRows - 1);

    const float* zr = Z + (size_t)rowA * 64 + q * 8;
    float4 z0 = *(const float4*)zr;
    float4 z1 = *(const float4*)(zr + 4);
    float4 z2 = *(const float4*)(zr + 32);
    float4 z3 = *(const float4*)(zr + 36);
    U8 ah0, al0, ah1, al1;
    cvp(z0.x, z0.y, ah0.u.x, al0.u.x);
    cvp(z0.z, z0.w, ah0.u.y, al0.u.y);
    cvp(z1.x, z1.y, ah0.u.z, al0.u.z);
    cvp(z1.z, z1.w, ah0.u.w, al0.u.w);
    cvp(z2.x, z2.y, ah1.u.x, al1.u.x);
    cvp(z2.z, z2.w, ah1.u.y, al1.u.y);
    cvp(z3.x, z3.y, ah1.u.z, al1.u.z);
    cvp(z3.z, z3.w, ah1.u.w, al1.u.w);

    float zz = z0.x*z0.x + z0.y*z0.y + z0.z*z0.z + z0.w*z0.w
             + z1.x*z1.x + z1.y*z1.y + z1.z*z1.z + z1.w*z1.w
             + z2.x*z2.x + z2.y*z2.y + z2.z*z2.z + z2.w*z2.w
             + z3.x*z3.x + z3.y*z3.y + z3.z*z3.z + z3.w*z3.w;
    zz += __shfl_xor(zz, 16);
    zz += __shfl_xor(zz, 32);

    float s0v = S[(size_t)rowA * 3 + 0];
    float s1v = S[(size_t)rowA * 3 + 1];
    float s2v = S[(size_t)rowA * 3 + 2];
    float cz = 0.5f * (zz + s0v * s0v + s1v * s1v + s2v * s2v) + cLog;

    U8 rsh, rsl;
    rsh.s = z8(); rsl.s = z8();
    if (lane < 16) {
        cvp(s0v, s1v, rsh.u.x, rsl.u.x);
        unsigned hw, lw;
        cvp(s2v, 1.0f, hw, lw);
        rsh.u.y = hw;
        rsl.u.y = lw & 0x0000ffffu;
    }

    f32x4 acc[NT];
#pragma unroll
    for (int t = 0; t < NT; ++t) { f32x4 zv = {0.f, 0.f, 0.f, 0.f}; acc[t] = zv; }

#pragma unroll
    for (int t = 0; t < NT; ++t) {
        short8 b0 = ldsBh[(t * 2 + 0) * 64 + lane];
        short8 b1 = ldsBh[(t * 2 + 1) * 64 + lane];
        short8 c0 = ldsBl[(t * 2 + 0) * 64 + lane];
        short8 c1 = ldsBl[(t * 2 + 1) * 64 + lane];
        uint2 bh2 = make_uint2(0, 0), bl2 = make_uint2(0, 0);
        if (lane < 16) { bh2 = ldsB2h[t * 16 + lane]; bl2 = ldsB2l[t * 16 + lane]; }
        U8 cmh, cml;
        cmh.s = z8(); cml.s = z8();
        cmh.u.x = bh2.x; cmh.u.y = bh2.y;
        cml.u.x = bl2.x; cml.u.y = bl2.y;

        acc[t] = MFMA16(b0, ah0.s, acc[t], 0, 0, 0);
        acc[t] = MFMA16(b1, ah1.s, acc[t], 0, 0, 0);
        acc[t] = MFMA16(b0, al0.s, acc[t], 0, 0, 0);
        acc[t] = MFMA16(b1, al1.s, acc[t], 0, 0, 0);
        acc[t] = MFMA16(c0, ah0.s, acc[t], 0, 0, 0);
        acc[t] = MFMA16(c1, ah1.s, acc[t], 0, 0, 0);
        acc[t] = MFMA16(cmh.s, rsh.s, acc[t], 0, 0, 0);
        acc[t] = MFMA16(cmh.s, rsl.s, acc[t], 0, 0, 0);
        acc[t] = MFMA16(cml.s, rsh.s, acc[t], 0, 0, 0);
    }

    const bool padQ = (q >= 2);
    float mx = -1e30f;
#pragma unroll
    for (int t = 0; t < NT; ++t) {
#pragma unroll
        for (int r = 0; r < 4; ++r) {
            float v = acc[t][r];
            if (t == 12 && padQ) v = -1e30f;
            acc[t][r] = v;
            mx = fmaxf(mx, v);
        }
    }
    mx = fmaxf(mx, __shfl_xor(mx, 16));
    mx = fmaxf(mx, __shfl_xor(mx, 32));
    float sl = 0.f, pl = 0.f;
#pragma unroll
    for (int t = 0; t < NT; ++t) {
#pragma unroll
        for (int r = 0; r < 4; ++r) {
            float v = acc[t][r];
            float ee = __expf(v - mx);
            sl += ee;
            pl = fmaf(ee, v, pl);
            acc[t][r] = ee;
        }
    }
    sl += __shfl_xor(sl, 16);
    sl += __shfl_xor(sl, 32);
    pl += __shfl_xor(pl, 16);
    pl += __shfl_xor(pl, 32);
    float inv = 1.0f / sl;

    if (row < sRows) {
        unsigned char* qp = Qc8 + (size_t)row * Q8STRIDE + q * 4;
#pragma unroll
        for (int t = 0; t < NT; ++t) {
            unsigned w = 0;
            if (t < 12 || !padQ) {
                float c0 = fminf(fmaxf(acc[t][0] * inv, 1e-6f), 1.0f - 1e-6f) * 1024.0f;
                float c1 = fminf(fmaxf(acc[t][1] * inv, 1e-6f), 1.0f - 1e-6f) * 1024.0f;
                float c2 = fminf(fmaxf(acc[t][2] * inv, 1e-6f), 1.0f - 1e-6f) * 1024.0f;
                float c3 = fminf(fmaxf(acc[t][3] * inv, 1e-6f), 1.0f - 1e-6f) * 1024.0f;
                unsigned ua = pkrtz_u(c0, c1);
                unsigned ub = pkrtz_u(c2, c3);
                unsigned t0 = ua + 0x007f007fu + ((ua >> 8) & 0x00010001u);
                unsigned t1 = ub + 0x007f007fu + ((ub >> 8) & 0x00010001u);
                w = __builtin_amdgcn_perm(t1, t0, 0x07050301u);
            }
            *(unsigned*)(qp + t * 16) = w;
        }
        // zero-fill pad comps 208..255 (kd reads the full 256B row)
        *(unsigned*)(qp + 13 * 16) = 0u;
        *(unsigned*)(qp + 14 * 16) = 0u;
        *(unsigned*)(qp + 15 * 16) = 0u;
        if (lane < 16) pointbuf[row] = cz - pl * inv;
    }
}

// k_doublet R16 (== R14): 16 lanes per row, 4 rows per wave. Lane l16 owns comps
// [l16*16, l16*16+16) via one uint4; decode via perm, dot via fdot2, reduction
// via 4 DPP row_ror adds within the 16-lane group.
__global__ __launch_bounds__(512, 8) void
k_doublet(const unsigned char* __restrict__ Qc8, const float* __restrict__ pointbuf,
          const int* __restrict__ D, float* __restrict__ out, int sRows)
{
    const int lane = threadIdx.x & 63;
    const int wave = threadIdx.x >> 6;
    const int g = lane >> 4;        // row group within wave
    const int l16 = lane & 15;
    const int row = blockIdx.x * 32 + wave * 4 + g;
    if (row >= sRows) return;

    const float LN2_20 = 13.862943611198906f;   // own,nb both x1024 -> co x 2^20

    const int* dp = D + (size_t)row * NNB;
    int2 d01 = *(const int2*)dp;
    int2 d23 = *(const int2*)(dp + 2);
    int2 d45 = *(const int2*)(dp + 4);
    const int dj[6] = { d01.x, d01.y, d23.x, d23.y, d45.x, d45.y };

    const unsigned off = (unsigned)l16 * 16u;
    uint4 ow = *(const uint4*)(Qc8 + (size_t)row * Q8STRIDE + off);
    uint4 nb[NNB];
#pragma unroll
    for (int j = 0; j < NNB; ++j) {
        int dd = (dj[j] >= 0) ? dj[j] : row;
        nb[j] = *(const uint4*)(Qc8 + (size_t)dd * Q8STRIDE + off);
    }

    unsigned o0 = e5pair_lo(ow.x), o1 = e5pair_hi(ow.x);
    unsigned o2 = e5pair_lo(ow.y), o3 = e5pair_hi(ow.y);
    unsigned o4 = e5pair_lo(ow.z), o5 = e5pair_hi(ow.z);
    unsigned o6 = e5pair_lo(ow.w), o7 = e5pair_hi(ow.w);

    float dbl = 0.f;
#pragma unroll
    for (int j = 0; j < NNB; ++j) {
        float t = 0.f;
#if __has_builtin(__builtin_amdgcn_fdot2)
        t = __builtin_amdgcn_fdot2(as_h2(o0), as_h2(e5pair_lo(nb[j].x)), t, false);
        t = __builtin_amdgcn_fdot2(as_h2(o1), as_h2(e5pair_hi(nb[j].x)), t, false);
        t = __builtin_amdgcn_fdot2(as_h2(o2), as_h2(e5pair_lo(nb[j].y)), t, false);
        t = __builtin_amdgcn_fdot2(as_h2(o3), as_h2(e5pair_hi(nb[j].y)), t, false);
        t = __builtin_amdgcn_fdot2(as_h2(o4), as_h2(e5pair_lo(nb[j].z)), t, false);
        t = __builtin_amdgcn_fdot2(as_h2(o5), as_h2(e5pair_hi(nb[j].z)), t, false);
        t = __builtin_amdgcn_fdot2(as_h2(o6), as_h2(e5pair_lo(nb[j].w)), t, false);
        t = __builtin_amdgcn_fdot2(as_h2(o7), as_h2(e5pair_hi(nb[j].w)), t, false);
#else
        {
            unsigned ov[8] = { o0, o1, o2, o3, o4, o5, o6, o7 };
            unsigned bv[8] = { e5pair_lo(nb[j].x), e5pair_hi(nb[j].x),
                               e5pair_lo(nb[j].y), e5pair_hi(nb[j].y),
                               e5pair_lo(nb[j].z), e5pair_hi(nb[j].z),
                               e5pair_lo(nb[j].w), e5pair_hi(nb[j].w) };
#pragma unroll
            for (int k = 0; k < 8; ++k) {
                half2v a = as_h2(ov[k]), b = as_h2(bv[k]);
                t = fmaf((float)a[0], (float)b[0], t);
                t = fmaf((float)a[1], (float)b[1], t);
            }
        }
#endif
        DPP_ROR_ADD(t, 0x128);   // row_ror:8
        DPP_ROR_ADD(t, 0x124);   // row_ror:4
        DPP_ROR_ADD(t, 0x122);   // row_ror:2
        DPP_ROR_ADD(t, 0x121);   // row_ror:1
        if (dj[j] >= 0) dbl += LN2_20 - __logf(t);
    }

    if (l16 == 0) out[row] = pointbuf[row] + dbl;
}

extern "C" void kernel_launch(void* const* d_in, const int* in_sizes, int n_in,
                              void* d_out, int out_size, void* d_ws, size_t ws_size,
                              hipStream_t stream) {
    const float* Z     = (const float*)d_in[0];
    const float* S     = (const float*)d_in[1];
    const int*   D     = (const int*)d_in[2];
    const float* selmu = (const float*)d_in[3];
    const float* spamu = (const float*)d_in[4];
    float* out = (float*)d_out;
    const int s = out_size;                    // 60000

    unsigned char* Qc8 = (unsigned char*)d_ws;                   // s*256 B = 15.36 MB
    float* pointbuf = (float*)((char*)d_ws + (size_t)s * Q8STRIDE);

    const int mTiles = (s + 15) / 16;          // 3750
    const int grid1 = (mTiles + 7) / 8;        // 469
    k_point<<<grid1, 512, 0, stream>>>(Z, S, selmu, spamu, Qc8, pointbuf, s, mTiles);

    const int grid2 = (s + 31) / 32;           // 1875: 4 rows/wave, 8 waves/block
    k_doublet<<<grid2, 512, 0, stream>>>(Qc8, pointbuf, D, out, s);
}